// Round 1
// baseline (494.277 us; speedup 1.0000x reference)
//
#include <hip/hip_runtime.h>

#define S 2048
#define Dh 64
#define NH 16
#define SD (S*Dh)                 // 131072 elements per head plane
#define SSZ ((size_t)S*(size_t)S) // attention matrix elements per head

typedef __attribute__((ext_vector_type(4))) float f32x4;
typedef __attribute__((ext_vector_type(8))) short s16x8;

// workspace layout (byte offsets)
#define WSB_QSUM 0                          // 1024 f32 (4 KB)
#define WSB_RINV 4096                       // 16*2048 f32 (128 KB)
#define WSB_MASK 135168                     // bm_t: [32 kt][2048 q] u64 (512 KB)
#define WSB_QS   659456                     // NH*SD bf16 (4 MB)
#define WSB_KS   (WSB_QS + 4194304)
#define WSB_VT   (WSB_KS + 4194304)         // ends ~12.6 MB

__device__ __forceinline__ ushort f2bf(float x) {
    unsigned u = __builtin_bit_cast(unsigned, x);
    u = (u + 0x7fffu + ((u >> 16) & 1u)) >> 16;
    return (ushort)u;
}

// ---- Q column-softmax denominators: sum_s exp(q[h,s,d]) per (head,d) ------
__global__ void k_qsum(const float* __restrict__ q, float* __restrict__ qsum) {
    const int head  = blockIdx.x >> 5;
    const int chunk = blockIdx.x & 31;       // 64 s-values per chunk
    const int t = threadIdx.x;
    const int d = t & 63, sg = t >> 6;
    const float* qh = q + (size_t)head * SD;
    const int s0 = chunk * 64;
    float acc = 0.f;
#pragma unroll
    for (int i = 0; i < 16; ++i) {
        int s = s0 + sg + 4 * i;
        acc += __expf(qh[s * Dh + d]);
    }
    __shared__ float part[4][64];
    part[sg][d] = acc;
    __syncthreads();
    if (sg == 0)
        atomicAdd(&qsum[head * 64 + d], part[0][d] + part[1][d] + part[2][d] + part[3][d]);
}

// ---- Qs = exp(q)/colsum -> bf16 ------------------------------------------
__global__ void k_qnorm(const float* __restrict__ q, const float* __restrict__ qsum,
                        ushort* __restrict__ Qs) {
    const int gid = blockIdx.x * 256 + threadIdx.x;
    const int i0 = gid * 8;
    const int head = i0 >> 17;
    const int d0 = i0 & 63;
    const float4 a = ((const float4*)(q + i0))[0];
    const float4 b = ((const float4*)(q + i0))[1];
    const float* qs = qsum + head * 64 + d0;
    s16x8 o;
    o[0] = (short)f2bf(__expf(a.x) / qs[0]);
    o[1] = (short)f2bf(__expf(a.y) / qs[1]);
    o[2] = (short)f2bf(__expf(a.z) / qs[2]);
    o[3] = (short)f2bf(__expf(a.w) / qs[3]);
    o[4] = (short)f2bf(__expf(b.x) / qs[4]);
    o[5] = (short)f2bf(__expf(b.y) / qs[5]);
    o[6] = (short)f2bf(__expf(b.z) / qs[6]);
    o[7] = (short)f2bf(__expf(b.w) / qs[7]);
    *(s16x8*)(Qs + i0) = o;
}

// ---- K softmax over heads axis (8 values) -> bf16 ------------------------
__global__ void k_ksoft(const float* __restrict__ kin, ushort* __restrict__ Ks) {
    const int gid = blockIdx.x * 256 + threadIdx.x;
    const int n = gid >> 17;
    const int rem = gid & (SD - 1);
    const float* base = kin + (size_t)n * 8 * SD + rem;
    float x[8];
    float sum = 0.f;
#pragma unroll
    for (int h = 0; h < 8; ++h) { x[h] = __expf(base[(size_t)h * SD]); sum += x[h]; }
    const float inv = 1.f / sum;
    ushort* ob = Ks + (size_t)n * 8 * SD + rem;
#pragma unroll
    for (int h = 0; h < 8; ++h) ob[(size_t)h * SD] = f2bf(x[h] * inv);
}

// ---- V transpose per head: [k][d] f32 -> Vt[d][k] bf16 -------------------
__global__ void k_vt(const float* __restrict__ V, ushort* __restrict__ Vt) {
    const int head = blockIdx.x >> 5, kt = blockIdx.x & 31;
    const int t = threadIdx.x;
    __shared__ float sv[64 * 68];
    const float4* src = (const float4*)(V + (size_t)head * SD + (size_t)kt * 64 * 64);
#pragma unroll
    for (int i = 0; i < 4; ++i) {
        int idx = t + 256 * i;
        int row = idx >> 4, c4 = idx & 15;
        *(float4*)&sv[row * 68 + c4 * 4] = src[idx];
    }
    __syncthreads();
    const int d = t >> 2, seg = t & 3;
    s16x8 v0, v1;
#pragma unroll
    for (int j = 0; j < 8; ++j) v0[j] = (short)f2bf(sv[(seg * 16 + j) * 68 + d]);
#pragma unroll
    for (int j = 0; j < 8; ++j) v1[j] = (short)f2bf(sv[(seg * 16 + 8 + j) * 68 + d]);
    ushort* dst = Vt + (size_t)head * SD + (size_t)d * S + kt * 64 + seg * 16;
    *(s16x8*)dst = v0;
    *(s16x8*)(dst + 8) = v1;
}

// ---- mask int32 [S][S] -> TRANSPOSED bitmask bm_t[kt][q] uint64 ----------
// transposed layout makes the per-lane mask load in k_ctx/k_awrite a single
// coalesced u64 (16 consecutive q per 16 lanes).
__global__ void k_mask(const int* __restrict__ mask, unsigned long long* __restrict__ bmt) {
    const int t = threadIdx.x;
    const int g = blockIdx.x * 4 + (t >> 6);   // wave id 0..4095
    const int lane = t & 63;
#pragma unroll
    for (int it = 0; it < 16; ++it) {
        int w = g * 16 + it;                   // w = q*32 + kt
        int m = mask[(size_t)w * 64 + lane];
        unsigned long long b = __ballot(m != 0);
        if (lane == 0) bmt[(size_t)(w & 31) * S + (w >> 5)] = b;
    }
}

// ---- pass A: rowsum + normalized ctx -------------------------------------
// Swapped-operand design: sc = mfma(K, Q) => D[k_row][q_col], q = lane&15.
// Each wave owns 16 q-rows and HALF the kt tiles (kt parity = wave>>1); the
// softmax row-reduce is 2 shfl_xor, P repack for PV is WAVE-PRIVATE LDS.
// => zero __syncthreads in the kt loop; one barrier in the epilogue to merge
// the two kt-parity partials. K/V fragments read straight from L2/L1
// (per-XCD working set = 2 heads of K+V = 1 MB, L2-fit; head = blockIdx.x).
__global__ __launch_bounds__(256, 4) void k_ctx(
        const ushort* __restrict__ Qs, const ushort* __restrict__ Ks,
        const ushort* __restrict__ Vt, const unsigned long long* __restrict__ bmt,
        float* __restrict__ ctx, float* __restrict__ rinv) {
    const int head = blockIdx.x, qt = blockIdx.y;
    const int q0 = qt * 32;
    const int t = threadIdx.x;
    const int lane = t & 63, w = t >> 6;
    const int wq = w & 1, par = w >> 1;      // q-half, kt parity
    const int lm = lane & 15, lg = lane >> 4;
    const int q = q0 + 16 * wq + lm;

    __shared__ __align__(16) ushort Pl[4][16][72];     // wave-private P tile
    __shared__ __align__(16) float redo[2][64][20];    // parity-1 partial o
    __shared__ float redrs[2][16];                     // parity-1 partial rowsum

    const ushort* Qb = Qs + (size_t)head * SD;
    const ushort* Kb = Ks + (size_t)head * SD;
    const ushort* Vb = Vt + (size_t)head * SD;

    // Q fragment persistent in registers (B-operand: col=lm -> this lane's q)
    s16x8 bq[2];
#pragma unroll
    for (int h = 0; h < 2; ++h)
        bq[h] = *(const s16x8*)(Qb + (size_t)q * 64 + 32 * h + 8 * lg);

    // invariant row bases
    const ushort* kr[4];
    const ushort* vr[4];
#pragma unroll
    for (int j = 0; j < 4; ++j) kr[j] = Kb + (size_t)(16 * j + lm) * 64 + 8 * lg;
#pragma unroll
    for (int dj = 0; dj < 4; ++dj) vr[dj] = Vb + (size_t)(16 * dj + lm) * S + 8 * lg;

    f32x4 o[4];
#pragma unroll
    for (int dj = 0; dj < 4; ++dj) o[dj] = (f32x4){0.f, 0.f, 0.f, 0.f};
    float rs = 0.f;
    uint* prow = (uint*)&Pl[w][lm][0];

    for (int kt = par; kt < 32; kt += 2) {
        const int k0 = kt * 64;
        // swapped QK^T: A = K-frag (row=lm -> k), B = Q-frag (col=lm -> q)
        f32x4 sc[4];
#pragma unroll
        for (int j = 0; j < 4; ++j) sc[j] = (f32x4){0.f, 0.f, 0.f, 0.f};
#pragma unroll
        for (int h = 0; h < 2; ++h)
#pragma unroll
            for (int j = 0; j < 4; ++j) {
                s16x8 ak = *(const s16x8*)(kr[j] + (size_t)k0 * 64 + 32 * h);
                sc[j] = __builtin_amdgcn_mfma_f32_16x16x32_bf16(ak, bq[h], sc[j], 0, 0, 0);
            }
        // sc[j][r] = score[k = k0+16j+4lg+r][q]  (consecutive k per reg!)
        const unsigned long long m64 = bmt[(size_t)kt * S + q];
        float rsum = 0.f;
#pragma unroll
        for (int j = 0; j < 4; ++j)
#pragma unroll
            for (int p = 0; p < 2; ++p) {
                const int b0 = 16 * j + 4 * lg + 2 * p;
                const float e0 = ((m64 >> b0) & 1ULL) ? __expf(sc[j][2 * p]) : 0.f;
                const float e1 = ((m64 >> (b0 + 1)) & 1ULL) ? __expf(sc[j][2 * p + 1]) : 0.f;
                rsum += e0 + e1;
                prow[8 * j + 2 * lg + p] = ((uint)f2bf(e1) << 16) | (uint)f2bf(e0);
            }
        rsum += __shfl_xor(rsum, 16);   // sum across lg groups (k coverage)
        rsum += __shfl_xor(rsum, 32);
        rs += rsum;
        // PV (swapped): o = mfma(Vt-frag, P-frag) => D[d_row][q_col]
#pragma unroll
        for (int c = 0; c < 2; ++c) {
            const s16x8 pb = *(const s16x8*)&Pl[w][lm][32 * c + 8 * lg];
#pragma unroll
            for (int dj = 0; dj < 4; ++dj) {
                s16x8 av = *(const s16x8*)(vr[dj] + k0 + 32 * c);
                o[dj] = __builtin_amdgcn_mfma_f32_16x16x32_bf16(av, pb, o[dj], 0, 0, 0);
            }
        }
    }

    // merge the two kt-parity partials (single barrier in whole kernel)
    if (par == 1) {
        float* dst = &redo[wq][lane][0];
#pragma unroll
        for (int dj = 0; dj < 4; ++dj) *(f32x4*)&dst[dj * 4] = o[dj];
        if (lg == 0) redrs[wq][lm] = rs;
    }
    __syncthreads();
    if (par == 0) {
        const float inv = 1.f / (rs + redrs[wq][lm]);
        if (lg == 0) rinv[head * S + q] = inv;
        const float* src = &redo[wq][lane][0];
        float* cb = ctx + (size_t)head * SD + (size_t)q * 64;
#pragma unroll
        for (int dj = 0; dj < 4; ++dj) {
            f32x4 oo = (o[dj] + *(const f32x4*)&src[dj * 4]) * inv;
            *(f32x4*)(cb + 16 * dj + 4 * lg) = oo;
        }
    }
}

// ---- pass B: recompute scores, write normalized A ------------------------
// Swapped-operand => lane holds 4 CONSECUTIVE k of its own q-row per f32x4:
// masked-exp-scale entirely in registers, direct f32x4 nontemporal store.
// NO LDS, NO barriers — pure stream, HBM-write-bound.
__global__ __launch_bounds__(256, 4) void k_awrite(
        const ushort* __restrict__ Qs, const ushort* __restrict__ Ks,
        const unsigned long long* __restrict__ bmt, const float* __restrict__ rinv,
        float* __restrict__ A) {
    const int head = blockIdx.x, qt = blockIdx.y, kc = blockIdx.z;
    const int q0 = qt * 64;
    const int t = threadIdx.x;
    const int lane = t & 63, wv = t >> 6;
    const int lm = lane & 15, lg = lane >> 4;
    const int q = q0 + 16 * wv + lm;

    const ushort* Qb = Qs + (size_t)head * SD;
    const ushort* Kb = Ks + (size_t)head * SD;
    float* Abase = A + (size_t)head * SSZ + (size_t)q * S;

    s16x8 bq[2];
#pragma unroll
    for (int h = 0; h < 2; ++h)
        bq[h] = *(const s16x8*)(Qb + (size_t)q * 64 + 32 * h + 8 * lg);
    const float invr = rinv[head * S + q];

    const ushort* kr[4];
#pragma unroll
    for (int j = 0; j < 4; ++j) kr[j] = Kb + (size_t)(16 * j + lm) * 64 + 8 * lg;

    for (int kt8 = 0; kt8 < 8; ++kt8) {
        const int k0 = kc * 512 + kt8 * 64;
        f32x4 sc[4];
#pragma unroll
        for (int j = 0; j < 4; ++j) sc[j] = (f32x4){0.f, 0.f, 0.f, 0.f};
#pragma unroll
        for (int h = 0; h < 2; ++h)
#pragma unroll
            for (int j = 0; j < 4; ++j) {
                s16x8 ak = *(const s16x8*)(kr[j] + (size_t)k0 * 64 + 32 * h);
                sc[j] = __builtin_amdgcn_mfma_f32_16x16x32_bf16(ak, bq[h], sc[j], 0, 0, 0);
            }
        const unsigned long long m64 = bmt[(size_t)(k0 >> 6) * S + q];
#pragma unroll
        for (int j = 0; j < 4; ++j) {
            f32x4 pv;
#pragma unroll
            for (int r = 0; r < 4; ++r) {
                const int b = 16 * j + 4 * lg + r;
                pv[r] = ((m64 >> b) & 1ULL) ? __expf(sc[j][r]) * invr : 0.f;
            }
            __builtin_nontemporal_store(pv, (f32x4*)&Abase[k0 + 16 * j + 4 * lg]);
        }
    }
}

extern "C" void kernel_launch(void* const* d_in, const int* in_sizes, int n_in,
                              void* d_out, int out_size, void* d_ws, size_t ws_size,
                              hipStream_t stream) {
    const float* q = (const float*)d_in[0];
    const float* k = (const float*)d_in[1];
    const float* v = (const float*)d_in[2];
    const int* mask = (const int*)d_in[3];
    float* out = (float*)d_out;   // [0, NH*SD) ctx ; [NH*SD, +NH*S*S) attn weights
    char* ws = (char*)d_ws;

    float* qsum = (float*)(ws + WSB_QSUM);
    float* rinv = (float*)(ws + WSB_RINV);
    unsigned long long* bm = (unsigned long long*)(ws + WSB_MASK);
    ushort* Qs = (ushort*)(ws + WSB_QS);
    ushort* Ks = (ushort*)(ws + WSB_KS);
    ushort* Vt = (ushort*)(ws + WSB_VT);

    (void)hipMemsetAsync(d_ws, 0, 4096, stream);
    k_qsum<<<512, 256, 0, stream>>>(q, qsum);
    k_mask<<<1024, 256, 0, stream>>>(mask, bm);
    k_qnorm<<<1024, 256, 0, stream>>>(q, qsum, Qs);
    k_ksoft<<<1024, 256, 0, stream>>>(k, Ks);
    k_vt<<<512, 256, 0, stream>>>(v, Vt);
    k_ctx<<<dim3(16, 64), 256, 0, stream>>>(Qs, Ks, Vt, bm, out, rinv);
    k_awrite<<<dim3(16, 32, 4), 256, 0, stream>>>(Qs, Ks, bm, rinv, out + (size_t)NH * SD);
}

// Round 2
// 420.715 us; speedup vs baseline: 1.1748x; 1.1748x over previous
//
#include <hip/hip_runtime.h>

#define S 2048
#define Dh 64
#define NH 16
#define SD (S*Dh)                 // 131072 elements per head plane
#define SSZ ((size_t)S*(size_t)S) // attention matrix elements per head

typedef __attribute__((ext_vector_type(4))) float f32x4;
typedef __attribute__((ext_vector_type(8))) short s16x8;

// workspace layout (byte offsets)
#define WSB_QSUM 0                          // 1024 f32 (4 KB)
#define WSB_RINV 4096                       // 16*2048 f32 (128 KB)
#define WSB_MASK 135168                     // bm_t: [32 kt][2048 q] u64 (512 KB)
#define WSB_QS   659456                     // NH*SD bf16 (4 MB)
#define WSB_KS   (WSB_QS + 4194304)
#define WSB_VT   (WSB_KS + 4194304)         // ends ~12.6 MB

__device__ __forceinline__ ushort f2bf(float x) {
    unsigned u = __builtin_bit_cast(unsigned, x);
    u = (u + 0x7fffu + ((u >> 16) & 1u)) >> 16;
    return (ushort)u;
}

// async 16B global -> LDS (linear dest: wave base + lane*16)
__device__ __forceinline__ void gload_lds16(const ushort* g, ushort* l) {
    __builtin_amdgcn_global_load_lds(
        (const __attribute__((address_space(1))) unsigned int*)(const void*)g,
        (__attribute__((address_space(3))) unsigned int*)(void*)l,
        16, 0, 0);
}

// ---- Q column-softmax denominators: sum_s exp(q[h,s,d]) per (head,d) ------
__global__ void k_qsum(const float* __restrict__ q, float* __restrict__ qsum) {
    const int head  = blockIdx.x >> 5;
    const int chunk = blockIdx.x & 31;       // 64 s-values per chunk
    const int t = threadIdx.x;
    const int d = t & 63, sg = t >> 6;
    const float* qh = q + (size_t)head * SD;
    const int s0 = chunk * 64;
    float acc = 0.f;
#pragma unroll
    for (int i = 0; i < 16; ++i) {
        int s = s0 + sg + 4 * i;
        acc += __expf(qh[s * Dh + d]);
    }
    __shared__ float part[4][64];
    part[sg][d] = acc;
    __syncthreads();
    if (sg == 0)
        atomicAdd(&qsum[head * 64 + d], part[0][d] + part[1][d] + part[2][d] + part[3][d]);
}

// ---- Qs = exp(q)/colsum -> bf16 ------------------------------------------
__global__ void k_qnorm(const float* __restrict__ q, const float* __restrict__ qsum,
                        ushort* __restrict__ Qs) {
    const int gid = blockIdx.x * 256 + threadIdx.x;
    const int i0 = gid * 8;
    const int head = i0 >> 17;
    const int d0 = i0 & 63;
    const float4 a = ((const float4*)(q + i0))[0];
    const float4 b = ((const float4*)(q + i0))[1];
    const float* qs = qsum + head * 64 + d0;
    s16x8 o;
    o[0] = (short)f2bf(__expf(a.x) / qs[0]);
    o[1] = (short)f2bf(__expf(a.y) / qs[1]);
    o[2] = (short)f2bf(__expf(a.z) / qs[2]);
    o[3] = (short)f2bf(__expf(a.w) / qs[3]);
    o[4] = (short)f2bf(__expf(b.x) / qs[4]);
    o[5] = (short)f2bf(__expf(b.y) / qs[5]);
    o[6] = (short)f2bf(__expf(b.z) / qs[6]);
    o[7] = (short)f2bf(__expf(b.w) / qs[7]);
    *(s16x8*)(Qs + i0) = o;
}

// ---- K softmax over heads axis (8 values) -> bf16 ------------------------
__global__ void k_ksoft(const float* __restrict__ kin, ushort* __restrict__ Ks) {
    const int gid = blockIdx.x * 256 + threadIdx.x;
    const int n = gid >> 17;
    const int rem = gid & (SD - 1);
    const float* base = kin + (size_t)n * 8 * SD + rem;
    float x[8];
    float sum = 0.f;
#pragma unroll
    for (int h = 0; h < 8; ++h) { x[h] = __expf(base[(size_t)h * SD]); sum += x[h]; }
    const float inv = 1.f / sum;
    ushort* ob = Ks + (size_t)n * 8 * SD + rem;
#pragma unroll
    for (int h = 0; h < 8; ++h) ob[(size_t)h * SD] = f2bf(x[h] * inv);
}

// ---- V transpose per head: [k][d] f32 -> Vt[d][k] bf16 -------------------
__global__ void k_vt(const float* __restrict__ V, ushort* __restrict__ Vt) {
    const int head = blockIdx.x >> 5, kt = blockIdx.x & 31;
    const int t = threadIdx.x;
    __shared__ float sv[64 * 68];
    const float4* src = (const float4*)(V + (size_t)head * SD + (size_t)kt * 64 * 64);
#pragma unroll
    for (int i = 0; i < 4; ++i) {
        int idx = t + 256 * i;
        int row = idx >> 4, c4 = idx & 15;
        *(float4*)&sv[row * 68 + c4 * 4] = src[idx];
    }
    __syncthreads();
    const int d = t >> 2, seg = t & 3;
    s16x8 v0, v1;
#pragma unroll
    for (int j = 0; j < 8; ++j) v0[j] = (short)f2bf(sv[(seg * 16 + j) * 68 + d]);
#pragma unroll
    for (int j = 0; j < 8; ++j) v1[j] = (short)f2bf(sv[(seg * 16 + 8 + j) * 68 + d]);
    ushort* dst = Vt + (size_t)head * SD + (size_t)d * S + kt * 64 + seg * 16;
    *(s16x8*)dst = v0;
    *(s16x8*)(dst + 8) = v1;
}

// ---- mask int32 [S][S] -> TRANSPOSED bitmask bm_t[kt][q] uint64 ----------
__global__ void k_mask(const int* __restrict__ mask, unsigned long long* __restrict__ bmt) {
    const int t = threadIdx.x;
    const int g = blockIdx.x * 4 + (t >> 6);   // wave id 0..4095
    const int lane = t & 63;
#pragma unroll
    for (int it = 0; it < 16; ++it) {
        int w = g * 16 + it;                   // w = q*32 + kt
        int m = mask[(size_t)w * 64 + lane];
        unsigned long long b = __ballot(m != 0);
        if (lane == 0) bmt[(size_t)(w & 31) * S + (w >> 5)] = b;
    }
}

// ---- pass A: rowsum + normalized ctx -------------------------------------
// Hybrid: LDS-staged K/V tiles (global_load_lds, XOR-swizzled both sides) +
// swapped-operand MFMA (D col = q = lane&15). Waves: wq = q-half (16 q),
// kh = k-half (32 k). P is WAVE-PRIVATE (tiny LDS, no barrier), rowsum via
// 2 shfl_xor. 2 barriers per k-tile (was 3); kh-partials merged in epilogue.
__global__ __launch_bounds__(256, 4) void k_ctx(
        const ushort* __restrict__ Qs, const ushort* __restrict__ Ks,
        const ushort* __restrict__ Vt, const unsigned long long* __restrict__ bmt,
        float* __restrict__ ctx, float* __restrict__ rinv) {
    const int head = blockIdx.x, qt = blockIdx.y;
    const int q0 = qt * 32;
    const int t = threadIdx.x;
    const int lane = t & 63, w = t >> 6;
    const int wq = w & 1, kh = w >> 1;
    const int lm = lane & 15, lg = lane >> 4;
    const int q = q0 + 16 * wq + lm;

    __shared__ __align__(16) char smem[21760];
    ushort* sK = (ushort*)smem;                 // [64][64] linear, swizzled content
    ushort* sV = (ushort*)(smem + 8192);        // [64][64]
    ushort* Pl = (ushort*)(smem + 16384);       // [4 waves][16 q][40]
    float*  redrs = (float*)(smem + 21504);     // [2][16]
    float*  redo  = (float*)smem;               // aliased [2][64][20] (epilogue only)

    const ushort* Qb = Qs + (size_t)head * SD;
    const ushort* Kb = Ks + (size_t)head * SD;
    const ushort* Vb = Vt + (size_t)head * SD;

    // Q fragment persistent in registers (B-operand: col = lm -> this lane's q)
    s16x8 bq[2];
#pragma unroll
    for (int h = 0; h < 2; ++h)
        bq[h] = *(const s16x8*)(Qb + (size_t)q * 64 + 32 * h + 8 * lg);

    f32x4 o[4];
#pragma unroll
    for (int dj = 0; dj < 4; ++dj) o[dj] = (f32x4){0.f, 0.f, 0.f, 0.f};
    float rs = 0.f;
    uint* prow = (uint*)&Pl[(w * 16 + lm) * 40];

    for (int kt = 0; kt < 32; ++kt) {
        const int k0 = kt * 64;
        __syncthreads();                         // prev tile fully consumed
#pragma unroll
        for (int i = 0; i < 2; ++i) {
            const int idx = t + 256 * i;
            const int row = idx >> 3, seg = idx & 7;
            const int sw = (seg ^ (row & 7)) * 8;   // pre-swizzled source chunk
            gload_lds16(Kb + (size_t)(k0 + row) * 64 + sw, &sK[idx * 8]);
            gload_lds16(Vb + (size_t)row * S + k0 + sw, &sV[idx * 8]);
        }
        __syncthreads();                         // drains vmcnt (gload_lds)

        // swapped QK^T: A = K rows (k), B = Q regs (col = own q)
        f32x4 sc[2];
        sc[0] = (f32x4){0.f, 0.f, 0.f, 0.f};
        sc[1] = (f32x4){0.f, 0.f, 0.f, 0.f};
#pragma unroll
        for (int h = 0; h < 2; ++h)
#pragma unroll
            for (int jj = 0; jj < 2; ++jj) {
                const int row = 16 * (2 * kh + jj) + lm;
                s16x8 ak = *(const s16x8*)&sK[row * 64 + (((4 * h + lg) ^ (lm & 7)) * 8)];
                sc[jj] = __builtin_amdgcn_mfma_f32_16x16x32_bf16(ak, bq[h], sc[jj], 0, 0, 0);
            }
        // sc[jj][r]: k = k0 + 32*kh + 16*jj + 4*lg + r,  q = own
        const unsigned long long m64 = bmt[(size_t)kt * S + q];
        float rsum = 0.f;
#pragma unroll
        for (int jj = 0; jj < 2; ++jj)
#pragma unroll
            for (int p = 0; p < 2; ++p) {
                const int kloc = 16 * jj + 4 * lg + 2 * p;   // within wave's 32 k
                const int kbit = 32 * kh + kloc;
                const float e0 = ((m64 >> kbit) & 1ULL) ? __expf(sc[jj][2 * p]) : 0.f;
                const float e1 = ((m64 >> (kbit + 1)) & 1ULL) ? __expf(sc[jj][2 * p + 1]) : 0.f;
                rsum += e0 + e1;
                prow[kloc >> 1] = ((uint)f2bf(e1) << 16) | (uint)f2bf(e0);
            }
        rsum += __shfl_xor(rsum, 16);
        rsum += __shfl_xor(rsum, 32);
        rs += rsum;

        // PV (swapped): A = V rows (d), B = own-q P frag (wave-private LDS)
        const s16x8 pb = *(const s16x8*)&Pl[(w * 16 + lm) * 40 + 8 * lg];
#pragma unroll
        for (int dj = 0; dj < 4; ++dj) {
            const int vrow = 16 * dj + lm;
            s16x8 av = *(const s16x8*)&sV[vrow * 64 + (((4 * kh + lg) ^ (lm & 7)) * 8)];
            o[dj] = __builtin_amdgcn_mfma_f32_16x16x32_bf16(av, pb, o[dj], 0, 0, 0);
        }
    }

    __syncthreads();                             // tiles done; safe to alias redo
    if (kh == 1) {
        float* dst = redo + (wq * 64 + lane) * 20;
#pragma unroll
        for (int dj = 0; dj < 4; ++dj) *(f32x4*)&dst[dj * 4] = o[dj];
        if (lg == 0) redrs[wq * 16 + lm] = rs;
    }
    __syncthreads();
    if (kh == 0) {
        const float inv = 1.f / (rs + redrs[wq * 16 + lm]);
        if (lg == 0) rinv[head * S + q] = inv;
        const float* src = redo + (wq * 64 + lane) * 20;
        float* cb = ctx + (size_t)head * SD + (size_t)q * 64;
#pragma unroll
        for (int dj = 0; dj < 4; ++dj) {
            f32x4 oo = (o[dj] + *(const f32x4*)&src[dj * 4]) * inv;
            *(f32x4*)(cb + 16 * dj + 4 * lg) = oo;
        }
    }
}

// ---- pass B: recompute scores, write normalized A ------------------------
// LDS-staged K (9 KB only) + swapped operands: masked-exp-scale in registers,
// direct f32x4 nontemporal stores (no sPf bounce, no sQ). Occupancy 6.
__global__ __launch_bounds__(256, 6) void k_awrite(
        const ushort* __restrict__ Qs, const ushort* __restrict__ Ks,
        const unsigned long long* __restrict__ bmt, const float* __restrict__ rinv,
        float* __restrict__ A) {
    const int head = blockIdx.x, qt = blockIdx.y, kc = blockIdx.z;
    const int q0 = qt * 64;
    const int t = threadIdx.x;
    const int lane = t & 63, wv = t >> 6;
    const int lm = lane & 15, lg = lane >> 4;
    const int q = q0 + 16 * wv + lm;

    __shared__ __align__(16) ushort sK[64 * 64];  // linear, swizzled content

    const ushort* Qb = Qs + (size_t)head * SD;
    const ushort* Kb = Ks + (size_t)head * SD;
    float* Aq = A + (size_t)head * SSZ + (size_t)q * S;

    s16x8 bq[2];
#pragma unroll
    for (int h = 0; h < 2; ++h)
        bq[h] = *(const s16x8*)(Qb + (size_t)q * 64 + 32 * h + 8 * lg);
    const float invr = rinv[head * S + q];

    for (int kt8 = 0; kt8 < 8; ++kt8) {
        const int k0 = kc * 512 + kt8 * 64;
        __syncthreads();
#pragma unroll
        for (int i = 0; i < 2; ++i) {
            const int idx = t + 256 * i;
            const int row = idx >> 3, seg = idx & 7;
            gload_lds16(Kb + (size_t)(k0 + row) * 64 + ((seg ^ (row & 7)) * 8), &sK[idx * 8]);
        }
        __syncthreads();

        f32x4 sc[4];
#pragma unroll
        for (int j = 0; j < 4; ++j) sc[j] = (f32x4){0.f, 0.f, 0.f, 0.f};
#pragma unroll
        for (int h = 0; h < 2; ++h)
#pragma unroll
            for (int j = 0; j < 4; ++j) {
                s16x8 ak = *(const s16x8*)&sK[(16 * j + lm) * 64 + (((4 * h + lg) ^ (lm & 7)) * 8)];
                sc[j] = __builtin_amdgcn_mfma_f32_16x16x32_bf16(ak, bq[h], sc[j], 0, 0, 0);
            }
        const unsigned long long m64 = bmt[(size_t)(k0 >> 6) * S + q];
#pragma unroll
        for (int j = 0; j < 4; ++j) {
            f32x4 pv;
#pragma unroll
            for (int r = 0; r < 4; ++r) {
                const int b = 16 * j + 4 * lg + r;
                pv[r] = ((m64 >> b) & 1ULL) ? __expf(sc[j][r]) * invr : 0.f;
            }
            __builtin_nontemporal_store(pv, (f32x4*)&Aq[k0 + 16 * j + 4 * lg]);
        }
    }
}

extern "C" void kernel_launch(void* const* d_in, const int* in_sizes, int n_in,
                              void* d_out, int out_size, void* d_ws, size_t ws_size,
                              hipStream_t stream) {
    const float* q = (const float*)d_in[0];
    const float* k = (const float*)d_in[1];
    const float* v = (const float*)d_in[2];
    const int* mask = (const int*)d_in[3];
    float* out = (float*)d_out;   // [0, NH*SD) ctx ; [NH*SD, +NH*S*S) attn weights
    char* ws = (char*)d_ws;

    float* qsum = (float*)(ws + WSB_QSUM);
    float* rinv = (float*)(ws + WSB_RINV);
    unsigned long long* bm = (unsigned long long*)(ws + WSB_MASK);
    ushort* Qs = (ushort*)(ws + WSB_QS);
    ushort* Ks = (ushort*)(ws + WSB_KS);
    ushort* Vt = (ushort*)(ws + WSB_VT);

    (void)hipMemsetAsync(d_ws, 0, 4096, stream);
    k_qsum<<<512, 256, 0, stream>>>(q, qsum);
    k_mask<<<1024, 256, 0, stream>>>(mask, bm);
    k_qnorm<<<1024, 256, 0, stream>>>(q, qsum, Qs);
    k_ksoft<<<1024, 256, 0, stream>>>(k, Ks);
    k_vt<<<512, 256, 0, stream>>>(v, Vt);
    k_ctx<<<dim3(16, 64), 256, 0, stream>>>(Qs, Ks, Vt, bm, out, rinv);
    k_awrite<<<dim3(16, 32, 4), 256, 0, stream>>>(Qs, Ks, bm, rinv, out + (size_t)NH * SD);
}

// Round 5
// 383.425 us; speedup vs baseline: 1.2891x; 1.0973x over previous
//
#include <hip/hip_runtime.h>

#define S 2048
#define Dh 64
#define NH 16
#define SD (S*Dh)                 // 131072 elements per head plane
#define SSZ ((size_t)S*(size_t)S) // attention matrix elements per head

typedef __attribute__((ext_vector_type(4))) float f32x4;
typedef __attribute__((ext_vector_type(8))) short s16x8;

// workspace layout (byte offsets)
#define WSB_QSUM 0                          // 1024 f32 (4 KB)
#define WSB_RINV 4096                       // 16*2048 f32 (128 KB)
#define WSB_MASK 135168                     // bm_t: [32 kt][2048 q] u64 (512 KB)
#define WSB_QS   659456                     // NH*SD bf16 (4 MB)
#define WSB_KS   (WSB_QS + 4194304)
#define WSB_VT   (WSB_KS + 4194304)         // ends ~12.6 MB

__device__ __forceinline__ ushort f2bf(float x) {
    unsigned u = __builtin_bit_cast(unsigned, x);
    u = (u + 0x7fffu + ((u >> 16) & 1u)) >> 16;
    return (ushort)u;
}

// async 16B global -> LDS (linear dest: wave base + lane*16)
__device__ __forceinline__ void gload_lds16(const ushort* g, ushort* l) {
    __builtin_amdgcn_global_load_lds(
        (const __attribute__((address_space(1))) unsigned int*)(const void*)g,
        (__attribute__((address_space(3))) unsigned int*)(void*)l,
        16, 0, 0);
}

// ---- Q column-softmax denominators: sum_s exp(q[h,s,d]) per (head,d) ------
__global__ void k_qsum(const float* __restrict__ q, float* __restrict__ qsum) {
    const int head  = blockIdx.x >> 5;
    const int chunk = blockIdx.x & 31;       // 64 s-values per chunk
    const int t = threadIdx.x;
    const int d = t & 63, sg = t >> 6;
    const float* qh = q + (size_t)head * SD;
    const int s0 = chunk * 64;
    float acc = 0.f;
#pragma unroll
    for (int i = 0; i < 16; ++i) {
        int s = s0 + sg + 4 * i;
        acc += __expf(qh[s * Dh + d]);
    }
    __shared__ float part[4][64];
    part[sg][d] = acc;
    __syncthreads();
    if (sg == 0)
        atomicAdd(&qsum[head * 64 + d], part[0][d] + part[1][d] + part[2][d] + part[3][d]);
}

// ---- Qs = exp(q)/colsum -> bf16 ------------------------------------------
__global__ void k_qnorm(const float* __restrict__ q, const float* __restrict__ qsum,
                        ushort* __restrict__ Qs) {
    const int gid = blockIdx.x * 256 + threadIdx.x;
    const int i0 = gid * 8;
    const int head = i0 >> 17;
    const int d0 = i0 & 63;
    const float4 a = ((const float4*)(q + i0))[0];
    const float4 b = ((const float4*)(q + i0))[1];
    const float* qs = qsum + head * 64 + d0;
    s16x8 o;
    o[0] = (short)f2bf(__expf(a.x) / qs[0]);
    o[1] = (short)f2bf(__expf(a.y) / qs[1]);
    o[2] = (short)f2bf(__expf(a.z) / qs[2]);
    o[3] = (short)f2bf(__expf(a.w) / qs[3]);
    o[4] = (short)f2bf(__expf(b.x) / qs[4]);
    o[5] = (short)f2bf(__expf(b.y) / qs[5]);
    o[6] = (short)f2bf(__expf(b.z) / qs[6]);
    o[7] = (short)f2bf(__expf(b.w) / qs[7]);
    *(s16x8*)(Qs + i0) = o;
}

// ---- K softmax over heads axis (8 values) -> bf16 ------------------------
__global__ void k_ksoft(const float* __restrict__ kin, ushort* __restrict__ Ks) {
    const int gid = blockIdx.x * 256 + threadIdx.x;
    const int n = gid >> 17;
    const int rem = gid & (SD - 1);
    const float* base = kin + (size_t)n * 8 * SD + rem;
    float x[8];
    float sum = 0.f;
#pragma unroll
    for (int h = 0; h < 8; ++h) { x[h] = __expf(base[(size_t)h * SD]); sum += x[h]; }
    const float inv = 1.f / sum;
    ushort* ob = Ks + (size_t)n * 8 * SD + rem;
#pragma unroll
    for (int h = 0; h < 8; ++h) ob[(size_t)h * SD] = f2bf(x[h] * inv);
}

// ---- V transpose per head: [k][d] f32 -> Vt[d][k] bf16 -------------------
__global__ void k_vt(const float* __restrict__ V, ushort* __restrict__ Vt) {
    const int head = blockIdx.x >> 5, kt = blockIdx.x & 31;
    const int t = threadIdx.x;
    __shared__ float sv[64 * 68];
    const float4* src = (const float4*)(V + (size_t)head * SD + (size_t)kt * 64 * 64);
#pragma unroll
    for (int i = 0; i < 4; ++i) {
        int idx = t + 256 * i;
        int row = idx >> 4, c4 = idx & 15;
        *(float4*)&sv[row * 68 + c4 * 4] = src[idx];
    }
    __syncthreads();
    const int d = t >> 2, seg = t & 3;
    s16x8 v0, v1;
#pragma unroll
    for (int j = 0; j < 8; ++j) v0[j] = (short)f2bf(sv[(seg * 16 + j) * 68 + d]);
#pragma unroll
    for (int j = 0; j < 8; ++j) v1[j] = (short)f2bf(sv[(seg * 16 + 8 + j) * 68 + d]);
    ushort* dst = Vt + (size_t)head * SD + (size_t)d * S + kt * 64 + seg * 16;
    *(s16x8*)dst = v0;
    *(s16x8*)(dst + 8) = v1;
}

// ---- mask int32 [S][S] -> TRANSPOSED bitmask bm_t[kt][q] uint64 ----------
__global__ void k_mask(const int* __restrict__ mask, unsigned long long* __restrict__ bmt) {
    const int t = threadIdx.x;
    const int g = blockIdx.x * 4 + (t >> 6);   // wave id 0..4095
    const int lane = t & 63;
#pragma unroll
    for (int it = 0; it < 16; ++it) {
        int w = g * 16 + it;                   // w = q*32 + kt
        int m = mask[(size_t)w * 64 + lane];
        unsigned long long b = __ballot(m != 0);
        if (lane == 0) bmt[(size_t)(w & 31) * S + (w >> 5)] = b;
    }
}

// ---- pass A: rowsum + normalized ctx (ROUND-2 VERIFIED VERSION) ----------
// LDS-staged K/V tiles (global_load_lds, XOR-swizzled both sides) +
// swapped-operand MFMA (D col = q = lane&15). Waves: wq = q-half (16 q),
// kh = k-half (32 k). P is WAVE-PRIVATE (tiny LDS, no barrier), rowsum via
// 2 shfl_xor. 2 barriers per k-tile; kh-partials merged in epilogue.
__global__ __launch_bounds__(256, 4) void k_ctx(
        const ushort* __restrict__ Qs, const ushort* __restrict__ Ks,
        const ushort* __restrict__ Vt, const unsigned long long* __restrict__ bmt,
        float* __restrict__ ctx, float* __restrict__ rinv) {
    const int head = blockIdx.x, qt = blockIdx.y;
    const int q0 = qt * 32;
    const int t = threadIdx.x;
    const int lane = t & 63, w = t >> 6;
    const int wq = w & 1, kh = w >> 1;
    const int lm = lane & 15, lg = lane >> 4;
    const int q = q0 + 16 * wq + lm;

    __shared__ __align__(16) char smem[21760];
    ushort* sK = (ushort*)smem;                 // [64][64] linear, swizzled content
    ushort* sV = (ushort*)(smem + 8192);        // [64][64]
    ushort* Pl = (ushort*)(smem + 16384);       // [4 waves][16 q][40]
    float*  redrs = (float*)(smem + 21504);     // [2][16]
    float*  redo  = (float*)smem;               // aliased [2][64][20] (epilogue only)

    const ushort* Qb = Qs + (size_t)head * SD;
    const ushort* Kb = Ks + (size_t)head * SD;
    const ushort* Vb = Vt + (size_t)head * SD;

    // Q fragment persistent in registers (B-operand: col = lm -> this lane's q)
    s16x8 bq[2];
#pragma unroll
    for (int h = 0; h < 2; ++h)
        bq[h] = *(const s16x8*)(Qb + (size_t)q * 64 + 32 * h + 8 * lg);

    f32x4 o[4];
#pragma unroll
    for (int dj = 0; dj < 4; ++dj) o[dj] = (f32x4){0.f, 0.f, 0.f, 0.f};
    float rs = 0.f;
    uint* prow = (uint*)&Pl[(w * 16 + lm) * 40];

    for (int kt = 0; kt < 32; ++kt) {
        const int k0 = kt * 64;
        __syncthreads();                         // prev tile fully consumed
#pragma unroll
        for (int i = 0; i < 2; ++i) {
            const int idx = t + 256 * i;
            const int row = idx >> 3, seg = idx & 7;
            const int sw = (seg ^ (row & 7)) * 8;   // pre-swizzled source chunk
            gload_lds16(Kb + (size_t)(k0 + row) * 64 + sw, &sK[idx * 8]);
            gload_lds16(Vb + (size_t)row * S + k0 + sw, &sV[idx * 8]);
        }
        __syncthreads();                         // drains vmcnt (gload_lds)

        // swapped QK^T: A = K rows (k), B = Q regs (col = own q)
        f32x4 sc[2];
        sc[0] = (f32x4){0.f, 0.f, 0.f, 0.f};
        sc[1] = (f32x4){0.f, 0.f, 0.f, 0.f};
#pragma unroll
        for (int h = 0; h < 2; ++h)
#pragma unroll
            for (int jj = 0; jj < 2; ++jj) {
                const int row = 16 * (2 * kh + jj) + lm;
                s16x8 ak = *(const s16x8*)&sK[row * 64 + (((4 * h + lg) ^ (lm & 7)) * 8)];
                sc[jj] = __builtin_amdgcn_mfma_f32_16x16x32_bf16(ak, bq[h], sc[jj], 0, 0, 0);
            }
        // sc[jj][r]: k = k0 + 32*kh + 16*jj + 4*lg + r,  q = own
        const unsigned long long m64 = bmt[(size_t)kt * S + q];
        float rsum = 0.f;
#pragma unroll
        for (int jj = 0; jj < 2; ++jj)
#pragma unroll
            for (int p = 0; p < 2; ++p) {
                const int kloc = 16 * jj + 4 * lg + 2 * p;   // within wave's 32 k
                const int kbit = 32 * kh + kloc;
                const float e0 = ((m64 >> kbit) & 1ULL) ? __expf(sc[jj][2 * p]) : 0.f;
                const float e1 = ((m64 >> (kbit + 1)) & 1ULL) ? __expf(sc[jj][2 * p + 1]) : 0.f;
                rsum += e0 + e1;
                prow[kloc >> 1] = ((uint)f2bf(e1) << 16) | (uint)f2bf(e0);
            }
        rsum += __shfl_xor(rsum, 16);
        rsum += __shfl_xor(rsum, 32);
        rs += rsum;

        // PV (swapped): A = V rows (d), B = own-q P frag (wave-private LDS)
        const s16x8 pb = *(const s16x8*)&Pl[(w * 16 + lm) * 40 + 8 * lg];
#pragma unroll
        for (int dj = 0; dj < 4; ++dj) {
            const int vrow = 16 * dj + lm;
            s16x8 av = *(const s16x8*)&sV[vrow * 64 + (((4 * kh + lg) ^ (lm & 7)) * 8)];
            o[dj] = __builtin_amdgcn_mfma_f32_16x16x32_bf16(av, pb, o[dj], 0, 0, 0);
        }
    }

    __syncthreads();                             // tiles done; safe to alias redo
    if (kh == 1) {
        float* dst = redo + (wq * 64 + lane) * 20;
#pragma unroll
        for (int dj = 0; dj < 4; ++dj) *(f32x4*)&dst[dj * 4] = o[dj];
        if (lg == 0) redrs[wq * 16 + lm] = rs;
    }
    __syncthreads();
    if (kh == 0) {
        const float inv = 1.f / (rs + redrs[wq * 16 + lm]);
        if (lg == 0) rinv[head * S + q] = inv;
        const float* src = redo + (wq * 64 + lane) * 20;
        float* cb = ctx + (size_t)head * SD + (size_t)q * 64;
#pragma unroll
        for (int dj = 0; dj < 4; ++dj) {
            f32x4 oo = (o[dj] + *(const f32x4*)&src[dj * 4]) * inv;
            *(f32x4*)(cb + 16 * dj + 4 * lg) = oo;
        }
    }
}

// ---- pass B: recompute scores, write normalized A ------------------------
// Double-buffered sK (1 barrier/tile) + swapped operands (masked-exp-scale
// in registers) + WAVE-PRIVATE sPf bounce to re-emit coalesced 256B-run
// nontemporal stores (no cross-wave sync on the bounce). No setprio.
__global__ __launch_bounds__(256, 4) void k_awrite(
        const ushort* __restrict__ Qs, const ushort* __restrict__ Ks,
        const unsigned long long* __restrict__ bmt, const float* __restrict__ rinv,
        float* __restrict__ A) {
    const int head = blockIdx.x, qt = blockIdx.y, kc = blockIdx.z;
    const int q0 = qt * 64;
    const int t = threadIdx.x;
    const int lane = t & 63, wv = t >> 6;
    const int lm = lane & 15, lg = lane >> 4;
    const int q = q0 + 16 * wv + lm;

    __shared__ __align__(16) char smem[33792];
    ushort* sK = (ushort*)smem;                // [2][4096] linear, swizzled content
    float* sP = (float*)(smem + 16384);        // [4 waves][16][68]

    const ushort* Qb = Qs + (size_t)head * SD;
    const ushort* Kb = Ks + (size_t)head * SD;
    float* Ah = A + (size_t)head * SSZ;

    auto stage = [&](int b, int k0) {
#pragma unroll
        for (int i = 0; i < 2; ++i) {
            const int idx = t + 256 * i;
            const int row = idx >> 3, seg = idx & 7;
            gload_lds16(Kb + (size_t)(k0 + row) * 64 + ((seg ^ (row & 7)) * 8),
                        &sK[b * 4096 + idx * 8]);
        }
    };

    s16x8 bq[2];
#pragma unroll
    for (int h = 0; h < 2; ++h)
        bq[h] = *(const s16x8*)(Qb + (size_t)q * 64 + 32 * h + 8 * lg);
    const float invr = rinv[head * S + q];
    float* sPw = &sP[wv * 16 * 68];

    stage(0, kc * 512);
    unsigned long long m64 = bmt[(size_t)(kc * 8) * S + q];
    __syncthreads();

    for (int kt8 = 0; kt8 < 8; ++kt8) {
        const int k0 = kc * 512 + kt8 * 64;
        const int cur = kt8 & 1;
        if (kt8 < 7) stage(cur ^ 1, k0 + 64);
        const unsigned long long m64n =
            (kt8 < 7) ? bmt[(size_t)((k0 >> 6) + 1) * S + q] : 0ULL;

        f32x4 sc[4];
#pragma unroll
        for (int j = 0; j < 4; ++j) sc[j] = (f32x4){0.f, 0.f, 0.f, 0.f};
#pragma unroll
        for (int h = 0; h < 2; ++h)
#pragma unroll
            for (int j = 0; j < 4; ++j) {
                s16x8 ak = *(const s16x8*)&sK[cur * 4096 + (16 * j + lm) * 64 +
                                              (((4 * h + lg) ^ (lm & 7)) * 8)];
                sc[j] = __builtin_amdgcn_mfma_f32_16x16x32_bf16(ak, bq[h], sc[j], 0, 0, 0);
            }

        // masked exp*inv in registers -> wave-private LDS row (own q = row lm)
#pragma unroll
        for (int j = 0; j < 4; ++j) {
            f32x4 pv;
#pragma unroll
            for (int r = 0; r < 4; ++r) {
                const int b = 16 * j + 4 * lg + r;
                pv[r] = ((m64 >> b) & 1ULL) ? __expf(sc[j][r]) * invr : 0.f;
            }
            *(f32x4*)&sPw[lm * 68 + 16 * j + 4 * lg] = pv;
        }
        // readback coalesced: per pass 4 rows x 256B contiguous runs
#pragma unroll
        for (int pass = 0; pass < 4; ++pass) {
            const int rr = (lane >> 4) + 4 * pass;
            f32x4 pv = *(const f32x4*)&sPw[rr * 68 + (lane & 15) * 4];
            __builtin_nontemporal_store(pv,
                (f32x4*)&Ah[(size_t)(q0 + 16 * wv + rr) * S + k0 + (lane & 15) * 4]);
        }
        __syncthreads();
        m64 = m64n;
    }
}

extern "C" void kernel_launch(void* const* d_in, const int* in_sizes, int n_in,
                              void* d_out, int out_size, void* d_ws, size_t ws_size,
                              hipStream_t stream) {
    const float* q = (const float*)d_in[0];
    const float* k = (const float*)d_in[1];
    const float* v = (const float*)d_in[2];
    const int* mask = (const int*)d_in[3];
    float* out = (float*)d_out;   // [0, NH*SD) ctx ; [NH*SD, +NH*S*S) attn weights
    char* ws = (char*)d_ws;

    float* qsum = (float*)(ws + WSB_QSUM);
    float* rinv = (float*)(ws + WSB_RINV);
    unsigned long long* bm = (unsigned long long*)(ws + WSB_MASK);
    ushort* Qs = (ushort*)(ws + WSB_QS);
    ushort* Ks = (ushort*)(ws + WSB_KS);
    ushort* Vt = (ushort*)(ws + WSB_VT);

    (void)hipMemsetAsync(d_ws, 0, 4096, stream);
    k_qsum<<<512, 256, 0, stream>>>(q, qsum);
    k_mask<<<1024, 256, 0, stream>>>(mask, bm);
    k_qnorm<<<1024, 256, 0, stream>>>(q, qsum, Qs);
    k_ksoft<<<1024, 256, 0, stream>>>(k, Ks);
    k_vt<<<512, 256, 0, stream>>>(v, Vt);
    k_ctx<<<dim3(16, 64), 256, 0, stream>>>(Qs, Ks, Vt, bm, out, rinv);
    k_awrite<<<dim3(16, 32, 4), 256, 0, stream>>>(Qs, Ks, bm, rinv, out + (size_t)NH * SD);
}

// Round 6
// 376.323 us; speedup vs baseline: 1.3134x; 1.0189x over previous
//
#include <hip/hip_runtime.h>

#define S 2048
#define Dh 64
#define NH 16
#define SD (S*Dh)                 // 131072 elements per head plane
#define SSZ ((size_t)S*(size_t)S) // attention matrix elements per head

typedef __attribute__((ext_vector_type(4))) float f32x4;
typedef __attribute__((ext_vector_type(8))) short s16x8;

// workspace layout (byte offsets)
#define WSB_QSUM 0                          // 1024 f32 (4 KB)
#define WSB_RINV 4096                       // 16*2048 f32 (128 KB)
#define WSB_MASK 135168                     // bm_t: [32 kt][2048 q] u64 (512 KB)
#define WSB_QS   659456                     // NH*SD bf16 (4 MB)
#define WSB_KS   (WSB_QS + 4194304)
#define WSB_VT   (WSB_KS + 4194304)         // ends ~12.6 MB

__device__ __forceinline__ ushort f2bf(float x) {
    unsigned u = __builtin_bit_cast(unsigned, x);
    u = (u + 0x7fffu + ((u >> 16) & 1u)) >> 16;
    return (ushort)u;
}

// async 16B global -> LDS (linear dest: wave base + lane*16)
__device__ __forceinline__ void gload_lds16(const ushort* g, ushort* l) {
    __builtin_amdgcn_global_load_lds(
        (const __attribute__((address_space(1))) unsigned int*)(const void*)g,
        (__attribute__((address_space(3))) unsigned int*)(void*)l,
        16, 0, 0);
}

// ---- Q column-softmax denominators: sum_s exp(q[h,s,d]) per (head,d) ------
__global__ void k_qsum(const float* __restrict__ q, float* __restrict__ qsum) {
    const int head  = blockIdx.x >> 5;
    const int chunk = blockIdx.x & 31;       // 64 s-values per chunk
    const int t = threadIdx.x;
    const int d = t & 63, sg = t >> 6;
    const float* qh = q + (size_t)head * SD;
    const int s0 = chunk * 64;
    float acc = 0.f;
#pragma unroll
    for (int i = 0; i < 16; ++i) {
        int s = s0 + sg + 4 * i;
        acc += __expf(qh[s * Dh + d]);
    }
    __shared__ float part[4][64];
    part[sg][d] = acc;
    __syncthreads();
    if (sg == 0)
        atomicAdd(&qsum[head * 64 + d], part[0][d] + part[1][d] + part[2][d] + part[3][d]);
}

// ---- Qs = exp(q)/colsum -> bf16 ------------------------------------------
__global__ void k_qnorm(const float* __restrict__ q, const float* __restrict__ qsum,
                        ushort* __restrict__ Qs) {
    const int gid = blockIdx.x * 256 + threadIdx.x;
    const int i0 = gid * 8;
    const int head = i0 >> 17;
    const int d0 = i0 & 63;
    const float4 a = ((const float4*)(q + i0))[0];
    const float4 b = ((const float4*)(q + i0))[1];
    const float* qs = qsum + head * 64 + d0;
    s16x8 o;
    o[0] = (short)f2bf(__expf(a.x) / qs[0]);
    o[1] = (short)f2bf(__expf(a.y) / qs[1]);
    o[2] = (short)f2bf(__expf(a.z) / qs[2]);
    o[3] = (short)f2bf(__expf(a.w) / qs[3]);
    o[4] = (short)f2bf(__expf(b.x) / qs[4]);
    o[5] = (short)f2bf(__expf(b.y) / qs[5]);
    o[6] = (short)f2bf(__expf(b.z) / qs[6]);
    o[7] = (short)f2bf(__expf(b.w) / qs[7]);
    *(s16x8*)(Qs + i0) = o;
}

// ---- K softmax over heads axis (8 values) -> bf16 ------------------------
__global__ void k_ksoft(const float* __restrict__ kin, ushort* __restrict__ Ks) {
    const int gid = blockIdx.x * 256 + threadIdx.x;
    const int n = gid >> 17;
    const int rem = gid & (SD - 1);
    const float* base = kin + (size_t)n * 8 * SD + rem;
    float x[8];
    float sum = 0.f;
#pragma unroll
    for (int h = 0; h < 8; ++h) { x[h] = __expf(base[(size_t)h * SD]); sum += x[h]; }
    const float inv = 1.f / sum;
    ushort* ob = Ks + (size_t)n * 8 * SD + rem;
#pragma unroll
    for (int h = 0; h < 8; ++h) ob[(size_t)h * SD] = f2bf(x[h] * inv);
}

// ---- V transpose per head: [k][d] f32 -> Vt[d][k] bf16 -------------------
__global__ void k_vt(const float* __restrict__ V, ushort* __restrict__ Vt) {
    const int head = blockIdx.x >> 5, kt = blockIdx.x & 31;
    const int t = threadIdx.x;
    __shared__ float sv[64 * 68];
    const float4* src = (const float4*)(V + (size_t)head * SD + (size_t)kt * 64 * 64);
#pragma unroll
    for (int i = 0; i < 4; ++i) {
        int idx = t + 256 * i;
        int row = idx >> 4, c4 = idx & 15;
        *(float4*)&sv[row * 68 + c4 * 4] = src[idx];
    }
    __syncthreads();
    const int d = t >> 2, seg = t & 3;
    s16x8 v0, v1;
#pragma unroll
    for (int j = 0; j < 8; ++j) v0[j] = (short)f2bf(sv[(seg * 16 + j) * 68 + d]);
#pragma unroll
    for (int j = 0; j < 8; ++j) v1[j] = (short)f2bf(sv[(seg * 16 + 8 + j) * 68 + d]);
    ushort* dst = Vt + (size_t)head * SD + (size_t)d * S + kt * 64 + seg * 16;
    *(s16x8*)dst = v0;
    *(s16x8*)(dst + 8) = v1;
}

// ---- mask int32 [S][S] -> TRANSPOSED bitmask bm_t[kt][q] uint64 ----------
__global__ void k_mask(const int* __restrict__ mask, unsigned long long* __restrict__ bmt) {
    const int t = threadIdx.x;
    const int g = blockIdx.x * 4 + (t >> 6);   // wave id 0..4095
    const int lane = t & 63;
#pragma unroll
    for (int it = 0; it < 16; ++it) {
        int w = g * 16 + it;                   // w = q*32 + kt
        int m = mask[(size_t)w * 64 + lane];
        unsigned long long b = __ballot(m != 0);
        if (lane == 0) bmt[(size_t)(w & 31) * S + (w >> 5)] = b;
    }
}

// ---- pass A: rowsum + normalized ctx -------------------------------------
// Double-buffered gload_lds staging (1 barrier/tile; next-tile loads issued
// before compute so they land under the MFMA+exp phase) + swapped-operand
// MFMA (D col = q = lane&15). Waves: wq = q-half, kh = k-half. P is
// wave-private; rowsum via 2 shfl_xor; mask prefetched one tile ahead.
// NO setprio (round-3 failure suspect). Pattern proven in round-5 k_awrite.
__global__ __launch_bounds__(256, 4) void k_ctx(
        const ushort* __restrict__ Qs, const ushort* __restrict__ Ks,
        const ushort* __restrict__ Vt, const unsigned long long* __restrict__ bmt,
        float* __restrict__ ctx, float* __restrict__ rinv) {
    const int head = blockIdx.x, qt = blockIdx.y;
    const int q0 = qt * 32;
    const int t = threadIdx.x;
    const int lane = t & 63, w = t >> 6;
    const int wq = w & 1, kh = w >> 1;
    const int lm = lane & 15, lg = lane >> 4;
    const int q = q0 + 16 * wq + lm;

    __shared__ __align__(16) char smem[38144];
    ushort* sK = (ushort*)smem;                 // [2][4096] linear, swizzled content
    ushort* sV = (ushort*)(smem + 16384);       // [2][4096]
    ushort* Pl = (ushort*)(smem + 32768);       // [4 waves][16 q][40]
    float*  redrs = (float*)(smem + 37888);     // [2][16]
    float*  redo  = (float*)smem;               // aliased [2][64][20] (epilogue only)

    const ushort* Qb = Qs + (size_t)head * SD;
    const ushort* Kb = Ks + (size_t)head * SD;
    const ushort* Vb = Vt + (size_t)head * SD;

    auto stage = [&](int b, int k0) {
#pragma unroll
        for (int i = 0; i < 2; ++i) {
            const int idx = t + 256 * i;
            const int row = idx >> 3, seg = idx & 7;
            const int sw = (seg ^ (row & 7)) * 8;   // pre-swizzled source chunk
            gload_lds16(Kb + (size_t)(k0 + row) * 64 + sw, &sK[b * 4096 + idx * 8]);
            gload_lds16(Vb + (size_t)row * S + k0 + sw, &sV[b * 4096 + idx * 8]);
        }
    };

    // Q fragment persistent in registers (B-operand: col = lm -> this lane's q)
    s16x8 bq[2];
#pragma unroll
    for (int h = 0; h < 2; ++h)
        bq[h] = *(const s16x8*)(Qb + (size_t)q * 64 + 32 * h + 8 * lg);

    f32x4 o[4];
#pragma unroll
    for (int dj = 0; dj < 4; ++dj) o[dj] = (f32x4){0.f, 0.f, 0.f, 0.f};
    float rs = 0.f;
    uint* prow = (uint*)&Pl[(w * 16 + lm) * 40];

    stage(0, 0);
    unsigned long long m64 = bmt[q];             // kt = 0
    __syncthreads();                             // buf0 ready

    for (int kt = 0; kt < 32; ++kt) {
        const int cur = kt & 1;
        if (kt < 31) stage(cur ^ 1, (kt + 1) * 64);   // next tile in flight
        const unsigned long long m64n = (kt < 31) ? bmt[(size_t)(kt + 1) * S + q] : 0ULL;
        const ushort* K = &sK[cur * 4096];
        const ushort* V = &sV[cur * 4096];

        // swapped QK^T: A = K rows (k), B = Q regs (col = own q)
        f32x4 sc[2];
        sc[0] = (f32x4){0.f, 0.f, 0.f, 0.f};
        sc[1] = (f32x4){0.f, 0.f, 0.f, 0.f};
#pragma unroll
        for (int h = 0; h < 2; ++h)
#pragma unroll
            for (int jj = 0; jj < 2; ++jj) {
                const int row = 16 * (2 * kh + jj) + lm;
                s16x8 ak = *(const s16x8*)&K[row * 64 + (((4 * h + lg) ^ (lm & 7)) * 8)];
                sc[jj] = __builtin_amdgcn_mfma_f32_16x16x32_bf16(ak, bq[h], sc[jj], 0, 0, 0);
            }

        // sc[jj][r]: k = kt*64 + 32*kh + 16*jj + 4*lg + r,  q = own
        float rsum = 0.f;
#pragma unroll
        for (int jj = 0; jj < 2; ++jj)
#pragma unroll
            for (int p = 0; p < 2; ++p) {
                const int kloc = 16 * jj + 4 * lg + 2 * p;   // within wave's 32 k
                const int kbit = 32 * kh + kloc;
                const float e0 = ((m64 >> kbit) & 1ULL) ? __expf(sc[jj][2 * p]) : 0.f;
                const float e1 = ((m64 >> (kbit + 1)) & 1ULL) ? __expf(sc[jj][2 * p + 1]) : 0.f;
                rsum += e0 + e1;
                prow[kloc >> 1] = ((uint)f2bf(e1) << 16) | (uint)f2bf(e0);
            }
        rsum += __shfl_xor(rsum, 16);
        rsum += __shfl_xor(rsum, 32);
        rs += rsum;

        // PV (swapped): A = V rows (d), B = own-q P frag (wave-private LDS)
        const s16x8 pb = *(const s16x8*)&Pl[(w * 16 + lm) * 40 + 8 * lg];
#pragma unroll
        for (int dj = 0; dj < 4; ++dj) {
            const int vrow = 16 * dj + lm;
            s16x8 av = *(const s16x8*)&V[vrow * 64 + (((4 * kh + lg) ^ (lm & 7)) * 8)];
            o[dj] = __builtin_amdgcn_mfma_f32_16x16x32_bf16(av, pb, o[dj], 0, 0, 0);
        }

        __syncthreads();     // next buffer ready; cur fully consumed by all
        m64 = m64n;
    }

    // loop's final barrier synced everyone; safe to alias redo over sK
    if (kh == 1) {
        float* dst = redo + (wq * 64 + lane) * 20;
#pragma unroll
        for (int dj = 0; dj < 4; ++dj) *(f32x4*)&dst[dj * 4] = o[dj];
        if (lg == 0) redrs[wq * 16 + lm] = rs;
    }
    __syncthreads();
    if (kh == 0) {
        const float inv = 1.f / (rs + redrs[wq * 16 + lm]);
        if (lg == 0) rinv[head * S + q] = inv;
        const float* src = redo + (wq * 64 + lane) * 20;
        float* cb = ctx + (size_t)head * SD + (size_t)q * 64;
#pragma unroll
        for (int dj = 0; dj < 4; ++dj) {
            f32x4 oo = (o[dj] + *(const f32x4*)&src[dj * 4]) * inv;
            *(f32x4*)(cb + 16 * dj + 4 * lg) = oo;
        }
    }
}

// ---- pass B: recompute scores, write normalized A (ROUND-5 VERIFIED) -----
// Double-buffered sK (1 barrier/tile) + swapped operands (masked-exp-scale
// in registers) + WAVE-PRIVATE sPf bounce to re-emit coalesced 256B-run
// nontemporal stores (no cross-wave sync on the bounce). No setprio.
__global__ __launch_bounds__(256, 4) void k_awrite(
        const ushort* __restrict__ Qs, const ushort* __restrict__ Ks,
        const unsigned long long* __restrict__ bmt, const float* __restrict__ rinv,
        float* __restrict__ A) {
    const int head = blockIdx.x, qt = blockIdx.y, kc = blockIdx.z;
    const int q0 = qt * 64;
    const int t = threadIdx.x;
    const int lane = t & 63, wv = t >> 6;
    const int lm = lane & 15, lg = lane >> 4;
    const int q = q0 + 16 * wv + lm;

    __shared__ __align__(16) char smem[33792];
    ushort* sK = (ushort*)smem;                // [2][4096] linear, swizzled content
    float* sP = (float*)(smem + 16384);        // [4 waves][16][68]

    const ushort* Qb = Qs + (size_t)head * SD;
    const ushort* Kb = Ks + (size_t)head * SD;
    float* Ah = A + (size_t)head * SSZ;

    auto stage = [&](int b, int k0) {
#pragma unroll
        for (int i = 0; i < 2; ++i) {
            const int idx = t + 256 * i;
            const int row = idx >> 3, seg = idx & 7;
            gload_lds16(Kb + (size_t)(k0 + row) * 64 + ((seg ^ (row & 7)) * 8),
                        &sK[b * 4096 + idx * 8]);
        }
    };

    s16x8 bq[2];
#pragma unroll
    for (int h = 0; h < 2; ++h)
        bq[h] = *(const s16x8*)(Qb + (size_t)q * 64 + 32 * h + 8 * lg);
    const float invr = rinv[head * S + q];
    float* sPw = &sP[wv * 16 * 68];

    stage(0, kc * 512);
    unsigned long long m64 = bmt[(size_t)(kc * 8) * S + q];
    __syncthreads();

    for (int kt8 = 0; kt8 < 8; ++kt8) {
        const int k0 = kc * 512 + kt8 * 64;
        const int cur = kt8 & 1;
        if (kt8 < 7) stage(cur ^ 1, k0 + 64);
        const unsigned long long m64n =
            (kt8 < 7) ? bmt[(size_t)((k0 >> 6) + 1) * S + q] : 0ULL;

        f32x4 sc[4];
#pragma unroll
        for (int j = 0; j < 4; ++j) sc[j] = (f32x4){0.f, 0.f, 0.f, 0.f};
#pragma unroll
        for (int h = 0; h < 2; ++h)
#pragma unroll
            for (int j = 0; j < 4; ++j) {
                s16x8 ak = *(const s16x8*)&sK[cur * 4096 + (16 * j + lm) * 64 +
                                              (((4 * h + lg) ^ (lm & 7)) * 8)];
                sc[j] = __builtin_amdgcn_mfma_f32_16x16x32_bf16(ak, bq[h], sc[j], 0, 0, 0);
            }

        // masked exp*inv in registers -> wave-private LDS row (own q = row lm)
#pragma unroll
        for (int j = 0; j < 4; ++j) {
            f32x4 pv;
#pragma unroll
            for (int r = 0; r < 4; ++r) {
                const int b = 16 * j + 4 * lg + r;
                pv[r] = ((m64 >> b) & 1ULL) ? __expf(sc[j][r]) * invr : 0.f;
            }
            *(f32x4*)&sPw[lm * 68 + 16 * j + 4 * lg] = pv;
        }
        // readback coalesced: per pass 4 rows x 256B contiguous runs
#pragma unroll
        for (int pass = 0; pass < 4; ++pass) {
            const int rr = (lane >> 4) + 4 * pass;
            f32x4 pv = *(const f32x4*)&sPw[rr * 68 + (lane & 15) * 4];
            __builtin_nontemporal_store(pv,
                (f32x4*)&Ah[(size_t)(q0 + 16 * wv + rr) * S + k0 + (lane & 15) * 4]);
        }
        __syncthreads();
        m64 = m64n;
    }
}

extern "C" void kernel_launch(void* const* d_in, const int* in_sizes, int n_in,
                              void* d_out, int out_size, void* d_ws, size_t ws_size,
                              hipStream_t stream) {
    const float* q = (const float*)d_in[0];
    const float* k = (const float*)d_in[1];
    const float* v = (const float*)d_in[2];
    const int* mask = (const int*)d_in[3];
    float* out = (float*)d_out;   // [0, NH*SD) ctx ; [NH*SD, +NH*S*S) attn weights
    char* ws = (char*)d_ws;

    float* qsum = (float*)(ws + WSB_QSUM);
    float* rinv = (float*)(ws + WSB_RINV);
    unsigned long long* bm = (unsigned long long*)(ws + WSB_MASK);
    ushort* Qs = (ushort*)(ws + WSB_QS);
    ushort* Ks = (ushort*)(ws + WSB_KS);
    ushort* Vt = (ushort*)(ws + WSB_VT);

    (void)hipMemsetAsync(d_ws, 0, 4096, stream);
    k_qsum<<<512, 256, 0, stream>>>(q, qsum);
    k_mask<<<1024, 256, 0, stream>>>(mask, bm);
    k_qnorm<<<1024, 256, 0, stream>>>(q, qsum, Qs);
    k_ksoft<<<1024, 256, 0, stream>>>(k, Ks);
    k_vt<<<512, 256, 0, stream>>>(v, Vt);
    k_ctx<<<dim3(16, 64), 256, 0, stream>>>(Qs, Ks, Vt, bm, out, rinv);
    k_awrite<<<dim3(16, 32, 4), 256, 0, stream>>>(Qs, Ks, bm, rinv, out + (size_t)NH * SD);
}